// Round 6
// baseline (185.892 us; speedup 1.0000x reference)
//
#include <hip/hip_runtime.h>

typedef _Float16 f16;
typedef _Float16 f16x2 __attribute__((ext_vector_type(2)));
typedef _Float16 f16x4 __attribute__((ext_vector_type(4)));
typedef _Float16 f16x8 __attribute__((ext_vector_type(8)));
typedef float f32x4 __attribute__((ext_vector_type(4)));
typedef int i32x4 __attribute__((ext_vector_type(4)));

#define MFMA(a, b, c) __builtin_amdgcn_mfma_f32_16x16x32_f16((a), (b), (c), 0, 0, 0)

typedef __attribute__((address_space(1))) const void gvoid;
typedef __attribute__((address_space(3))) void lvoid;

__device__ __forceinline__ void gload16(const void* g, void* l) {
    __builtin_amdgcn_global_load_lds((gvoid*)g, (lvoid*)l, 16, 0, 0);
}

// ---------------------------------------------------------------------------
// Kernel 1: cast f32 -> f16 for in_data (4M elems) and 4 weights (4x1M elems)
// ---------------------------------------------------------------------------
__global__ void cast_all(const float* __restrict__ x,
                         const float* __restrict__ w0, const float* __restrict__ w1,
                         const float* __restrict__ w2, const float* __restrict__ w3,
                         f16* __restrict__ xb, f16* __restrict__ wb) {
    const int NX = 4096 * 1024;
    int i = (blockIdx.x * 256 + threadIdx.x) * 4;
    if (i < NX) {
        float4 v = *(const float4*)(x + i);
        f16x4 o = {(f16)v.x, (f16)v.y, (f16)v.z, (f16)v.w};
        *(f16x4*)(xb + i) = o;
    } else {
        int j = i - NX;  // [0, 4M)
        const float* s = (j < (1 << 20)) ? w0 : (j < (2 << 20)) ? w1
                       : (j < (3 << 20)) ? w2 : w3;
        int loc = j & ((1 << 20) - 1);
        float4 v = *(const float4*)(s + loc);
        f16x4 o = {(f16)v.x, (f16)v.y, (f16)v.z, (f16)v.w};
        *(f16x4*)(wb + j) = o;
    }
}

// ---------------------------------------------------------------------------
// Kernel 2/4: GEMM C[m][n] = sum_k A[m][k]*B[n][k]   (x @ W.T form)
// M=4096, N=1024, K=1024. 128x128 tile, BK=64, 4 waves, global_load_lds.
// !FINAL: z=0 -> Q scaled by 0.125*log2(e) (exp2-domain softmax), z=1 -> K,
// z=2 -> V written TRANSPOSED into VT[b*1024 + n][2048 s].
// ---------------------------------------------------------------------------
template <bool FINAL>
__global__ void gemm_bt(const f16* __restrict__ A, const f16* __restrict__ Bw,
                        f16* __restrict__ Cf, f16* __restrict__ VTo,
                        float* __restrict__ Co, const float* __restrict__ bias) {
    __shared__ __align__(16) f16 As[128 * 64];
    __shared__ __align__(16) f16 Bs[128 * 64];
    const int tid = threadIdx.x;
    const int lane = tid & 63, wid = tid >> 6;
    const int lo = lane & 15, hi = lane >> 4;
    const int wr = wid >> 1, wc = wid & 1;
    const int m0 = blockIdx.x * 128, n0 = blockIdx.y * 128;
    const char* Ab = (const char*)A;
    const char* Bb = (const char*)(Bw + (size_t)blockIdx.z * (1024 * 1024));

    f32x4 acc[4][4];
#pragma unroll
    for (int i = 0; i < 4; ++i)
#pragma unroll
        for (int j = 0; j < 4; ++j) acc[i][j] = (f32x4){0.f, 0.f, 0.f, 0.f};

    for (int kt = 0; kt < 16; ++kt) {
        const int kb = kt * 128;  // byte offset along K (64 f16)
#pragma unroll
        for (int rr = 0; rr < 4; ++rr) {
            int o = rr * 4096 + tid * 16;
            int row = o >> 7, colB = o & 127;
            gload16(Ab + (size_t)(m0 + row) * 2048 + kb + colB, (char*)As + o);
            gload16(Bb + (size_t)(n0 + row) * 2048 + kb + colB, (char*)Bs + o);
        }
        __syncthreads();
#pragma unroll
        for (int kc = 0; kc < 2; ++kc) {
            f16x8 af[4], bf[4];
#pragma unroll
            for (int f = 0; f < 4; ++f)
                af[f] = *(const f16x8*)(As + (wr * 64 + f * 16 + lo) * 64 + kc * 32 + hi * 8);
#pragma unroll
            for (int f = 0; f < 4; ++f)
                bf[f] = *(const f16x8*)(Bs + (wc * 64 + f * 16 + lo) * 64 + kc * 32 + hi * 8);
#pragma unroll
            for (int i = 0; i < 4; ++i)
#pragma unroll
                for (int j = 0; j < 4; ++j) acc[i][j] = MFMA(af[i], bf[j], acc[i][j]);
        }
        __syncthreads();
    }

    const int mbase = m0 + wr * 64 + hi * 4;
    const int nbase = n0 + wc * 64 + lo;
    if (FINAL) {
#pragma unroll
        for (int j = 0; j < 4; ++j) {
            float bj = bias[nbase + j * 16];
#pragma unroll
            for (int i = 0; i < 4; ++i)
#pragma unroll
                for (int r = 0; r < 4; ++r)
                    Co[(size_t)(mbase + i * 16 + r) * 1024 + nbase + j * 16] =
                        acc[i][j][r] + bj;
        }
    } else if (blockIdx.z == 2) {
        // V written transposed: VT[(b*1024 + n)][s],  m = b*2048+s
#pragma unroll
        for (int i = 0; i < 4; ++i)
#pragma unroll
            for (int j = 0; j < 4; ++j)
#pragma unroll
                for (int r = 0; r < 4; ++r) {
                    int m = mbase + i * 16 + r, n = nbase + j * 16;
                    VTo[(size_t)((m >> 11) * 1024 + n) * 2048 + (m & 2047)] =
                        (f16)acc[i][j][r];
                }
    } else {
        // z==0: fold 1/sqrt(64) * log2(e) into Q (softmax runs in exp2 domain)
        const float osc = (blockIdx.z == 0) ? 0.18033688f : 1.0f;
        f16* Cz = Cf + (size_t)blockIdx.z * (4096 * 1024);
#pragma unroll
        for (int i = 0; i < 4; ++i)
#pragma unroll
            for (int j = 0; j < 4; ++j)
#pragma unroll
                for (int r = 0; r < 4; ++r)
                    Cz[(size_t)(mbase + i * 16 + r) * 1024 + nbase + j * 16] =
                        (f16)(acc[i][j][r] * osc);
    }
}

// ---------------------------------------------------------------------------
// Kernel 3: causal flash attention.
//  - swapped QK^T (S^T in registers: lane owns q=lo, kv=fj*16+hi*4+r)
//  - exp2-domain softmax, defer-max (thr=8), per-lane partial row-sum
//  - P redistributed to PV B-fragments IN REGISTERS (16 shfl + 8 selects);
//    PV = MFMA(V_Afrag, P_Bfrag) -> ctx^T, so corr & 1/l are lane-local
//  - K/V double-buffered (static arrays), one __syncthreads per kv-step
//  - LDS = 32 KB -> 4 blocks/CU capacity
// Grid (32 bh, 32 qt reversed) -> XCD = bh%8. 4 waves x 16 q-rows, KVBLK=64.
// ---------------------------------------------------------------------------
__global__ __launch_bounds__(256) void attn(const f16* __restrict__ Q,
                                            const f16* __restrict__ K,
                                            const f16* __restrict__ VT,
                                            f16* __restrict__ CTX) {
    __shared__ __align__(16) f16 K0[64 * 64];
    __shared__ __align__(16) f16 K1[64 * 64];
    __shared__ __align__(16) f16 V0[64 * 64];
    __shared__ __align__(16) f16 V1[64 * 64];
    const int tid = threadIdx.x;
    const int lane = tid & 63, w = tid >> 6;
    const int lo = lane & 15, hi = lane >> 4;
    const int bh = blockIdx.x;
    const int qt = 31 - blockIdx.y;  // heavy tiles dispatch first
    const int b = bh >> 4, h = bh & 15;
    const int qw0 = qt * 64 + w * 16;
    const int qglob = qw0 + lo;

    // Q fragments (B-operand of swapped QK^T): col=q=lo, k=kc*32+hi*8+j
    const f16* qrow = Q + (size_t)(b * 2048 + qw0 + lo) * 1024 + h * 64 + hi * 8;
    const f16x8 qa0 = *(const f16x8*)(qrow);
    const f16x8 qa1 = *(const f16x8*)(qrow + 32);

    // ctx^T: lane owns d = dblk*16 + hi*4 + r, q = qw0 + lo
    f32x4 ctx[4];
#pragma unroll
    for (int d = 0; d < 4; ++d) ctx[d] = (f32x4){0.f, 0.f, 0.f, 0.f};
    float mrun = -3e38f, lsum = 0.f;

    // shfl indices for the P redistribution (dest (hi,j2) <- src hi-group)
    const int idx0 = (2 * (hi & 1)) * 16 + lo;   // j2 in {0,1}
    const int idx1 = idx0 + 16;                  // j2 in {2,3}

    const char* Kb = (const char*)K;
    const char* Vb = (const char*)VT;

    auto stage = [&](f16* Kd, f16* Vd, int t) {
        const int kv0 = t * 64;
#pragma unroll
        for (int rr = 0; rr < 2; ++rr) {
            int o = rr * 4096 + tid * 16;
            int row = o >> 7;
            int colB = (o & 127) ^ ((row & 7) << 4);
            gload16(Kb + (size_t)(b * 2048 + kv0 + row) * 2048 + h * 128 + colB,
                    (char*)Kd + o);
            gload16(Vb + (size_t)(b * 1024 + h * 64 + row) * 4096 + (size_t)kv0 * 2 + colB,
                    (char*)Vd + o);
        }
    };

    auto compute = [&](const f16* Klb, const f16* Vlb, int t) {
        // ---- QK^T swapped: lane owns q=lo, kv = fj*16 + hi*4 + r ----
        f32x4 s4[4];
        __builtin_amdgcn_s_setprio(1);
#pragma unroll
        for (int fj = 0; fj < 4; ++fj) {
            f32x4 a = (f32x4){0.f, 0.f, 0.f, 0.f};
            const int kv = fj * 16 + lo;  // A-frag row
#pragma unroll
            for (int kc = 0; kc < 2; ++kc) {
                const int cb = (kc * 64 + hi * 16) ^ ((kv & 7) << 4);
                f16x8 kf = *(const f16x8*)((const char*)Klb + kv * 128 + cb);
                a = MFMA(kf, kc ? qa1 : qa0, a);
            }
            s4[fj] = a;
        }
        __builtin_amdgcn_s_setprio(0);

        // ---- softmax (exp2 domain), defer-max ----
        float pv[16];
        if (t == qt) {  // only the diagonal tile masks (wave-uniform branch)
#pragma unroll
            for (int fj = 0; fj < 4; ++fj)
#pragma unroll
                for (int r = 0; r < 4; ++r) {
                    const int kvg = t * 64 + fj * 16 + hi * 4 + r;
                    pv[fj * 4 + r] = (kvg > qglob) ? -1e38f : s4[fj][r];
                }
        } else {
#pragma unroll
            for (int fj = 0; fj < 4; ++fj)
#pragma unroll
                for (int r = 0; r < 4; ++r) pv[fj * 4 + r] = s4[fj][r];
        }

        // lane-local max of 16 (tree)
        float tm[8];
#pragma unroll
        for (int i = 0; i < 8; ++i) tm[i] = fmaxf(pv[i], pv[i + 8]);
#pragma unroll
        for (int i = 0; i < 4; ++i) tm[i] = fmaxf(tm[i], tm[i + 4]);
        const float mxl = fmaxf(fmaxf(tm[0], tm[1]), fmaxf(tm[2], tm[3]));

        if (__any(mxl > mrun + 8.0f)) {  // rescale path (rare after warmup)
            float mxg = fmaxf(mxl, __shfl_xor(mxl, 16));
            mxg = fmaxf(mxg, __shfl_xor(mxg, 32));
            const float mnew = fmaxf(mrun, mxg);
            const float corr = __builtin_amdgcn_exp2f(mrun - mnew);
            mrun = mnew;
            lsum *= corr;
#pragma unroll
            for (int d = 0; d < 4; ++d) {
                ctx[d][0] *= corr; ctx[d][1] *= corr;
                ctx[d][2] *= corr; ctx[d][3] *= corr;
            }
        }

#pragma unroll
        for (int i = 0; i < 16; ++i) pv[i] = __builtin_amdgcn_exp2f(pv[i] - mrun);
        // per-lane partial row-sum (cross-hi reduce deferred to epilogue)
        float ts[8];
#pragma unroll
        for (int i = 0; i < 8; ++i) ts[i] = pv[i] + pv[i + 8];
#pragma unroll
        for (int i = 0; i < 4; ++i) ts[i] = ts[i] + ts[i + 4];
        lsum += (ts[0] + ts[1]) + (ts[2] + ts[3]);

        // ---- pack P to f16x2 dwords: ph[fj][r2] = kv pair (fj*16+hi*4+2r2, +1)
        int ph[4][2];
#pragma unroll
        for (int fj = 0; fj < 4; ++fj)
#pragma unroll
            for (int r2 = 0; r2 < 2; ++r2) {
                f16x2 hpair = {(f16)pv[fj * 4 + 2 * r2], (f16)pv[fj * 4 + 2 * r2 + 1]};
                ph[fj][r2] = __builtin_bit_cast(int, hpair);
            }

        // ---- redistribute to B-frag: lane needs kv = kc*32 + hi*8 + (0..7)
        // dword(kc,j2) = shfl(ph[2kc + (hi>>1)][j2&1], (2(hi&1)+(j2>>1))*16+lo)
        f16x8 pb[2];
#pragma unroll
        for (int kc = 0; kc < 2; ++kc) {
            i32x4 dw;
#pragma unroll
            for (int j2 = 0; j2 < 4; ++j2) {
                const int idx = (j2 < 2) ? idx0 : idx1;
                int vA = __shfl(ph[2 * kc][j2 & 1], idx);
                int vB = __shfl(ph[2 * kc + 1][j2 & 1], idx);
                dw[j2] = (hi & 2) ? vB : vA;
            }
            pb[kc] = __builtin_bit_cast(f16x8, dw);
        }

        // ---- PV: ctx^T[d][q] += V^T[d][kv] * P^T[kv][q] ----
        __builtin_amdgcn_s_setprio(1);
#pragma unroll
        for (int df = 0; df < 4; ++df) {
            const int d = df * 16 + lo;  // A-frag row
#pragma unroll
            for (int kc = 0; kc < 2; ++kc) {
                const int cb = (kc * 64 + hi * 16) ^ ((d & 7) << 4);
                f16x8 vf = *(const f16x8*)((const char*)Vlb + d * 128 + cb);
                ctx[df] = MFMA(vf, pb[kc], ctx[df]);
            }
        }
        __builtin_amdgcn_s_setprio(0);
    };

    stage(&K0[0], &V0[0], 0);
    for (int t = 0; t <= qt; ++t) {
        __syncthreads();  // drains stage(t) loads (all waves) + full fence
        if ((t & 1) == 0) {
            if (t < qt) stage(&K1[0], &V1[0], t + 1);
            compute(&K0[0], &V0[0], t);
        } else {
            if (t < qt) stage(&K0[0], &V0[0], t + 1);
            compute(&K1[0], &V1[0], t);
        }
    }

    // epilogue: cross-hi row-sum, then lane-local normalize; lane owns
    // ctx^T[d = df*16 + hi*4 + r][q = qw0 + lo]
    float lt = lsum + __shfl_xor(lsum, 16);
    lt += __shfl_xor(lt, 32);
    const float inv = 1.0f / lt;
#pragma unroll
    for (int df = 0; df < 4; ++df) {
        f16x4 o = {(f16)(ctx[df][0] * inv), (f16)(ctx[df][1] * inv),
                   (f16)(ctx[df][2] * inv), (f16)(ctx[df][3] * inv)};
        *(f16x4*)(CTX + (size_t)(b * 2048 + qw0 + lo) * 1024 + h * 64 + df * 16 + hi * 4) = o;
    }
}

// ---------------------------------------------------------------------------
extern "C" void kernel_launch(void* const* d_in, const int* in_sizes, int n_in,
                              void* d_out, int out_size, void* d_ws, size_t ws_size,
                              hipStream_t stream) {
    const float* x = (const float*)d_in[0];
    const float* wq = (const float*)d_in[1];
    const float* wk = (const float*)d_in[2];
    const float* wv = (const float*)d_in[3];
    const float* wo = (const float*)d_in[4];
    const float* bo = (const float*)d_in[5];

    const size_t M1 = 1024 * 1024;
    f16* VT = (f16*)d_ws;          // 4M f16 (8 MB): V transposed [b*1024+n][2048]
    f16* Wh = VT + 4 * M1;         // 4M f16: Wq|Wk|Wv|Wo
    f16* QKV = Wh + 4 * M1;        // Q (4M) | K (4M)
    f16* Xb = QKV + 8 * M1;        // x cast; region later reused as CTX
    f16* Q = QKV;
    f16* K = QKV + 4 * M1;
    f16* CTX = QKV + 8 * M1;       // alias Xb: x dead after QKV GEMM
    float* out = (float*)d_out;

    cast_all<<<dim3(8192), dim3(256), 0, stream>>>(x, wq, wk, wv, wo, Xb, Wh);
    gemm_bt<false><<<dim3(32, 8, 3), dim3(256), 0, stream>>>(Xb, Wh, QKV, VT, nullptr, nullptr);
    attn<<<dim3(32, 32), dim3(256), 0, stream>>>(Q, K, VT, CTX);
    gemm_bt<true><<<dim3(32, 8, 1), dim3(256), 0, stream>>>(CTX, Wh + 3 * M1, nullptr, nullptr, out, bo);
}